// Round 1
// baseline (1186.982 us; speedup 1.0000x reference)
//
#include <hip/hip_runtime.h>

typedef unsigned short u16;
typedef unsigned int   u32;
typedef __attribute__((ext_vector_type(8))) __bf16 bf16x8;
typedef __attribute__((ext_vector_type(4))) float  f32x4;

#define MREL  8
#define DDIM  256
#define TROWS 32

// ws block layout: each block = 512 u16 = 1KB (one B-fragment set: 64 lanes x 8 bf16)
#define WPHI_B 1024
#define WB_B   2048
#define WC_B   2112
#define NBLK   2496

__device__ __forceinline__ u16 f2bf(float x) {
  u32 u = __float_as_uint(x);
  u += 0x7fffu + ((u >> 16) & 1u);   // RNE
  return (u16)(u >> 16);
}
__device__ __forceinline__ float bf2f(u16 h) {
  return __uint_as_float(((u32)h) << 16);
}

union U16x8 { u16 u[8]; uint4 q; bf16x8 v; };

// ---------------------------------------------------------------------------
// Prologue: swizzle all weights into bf16 MFMA B-fragment order.
// B-frag layout (16x16x32): lane l holds B[k=(l>>4)*8+j][col=l&15], j=0..7.
// Wmax blocks [0,1024): m*128 + ct*8 + ks   (ct 0..15, ks 0..7)
// Wphi blocks [1024,2048)
// Wb   blocks [2048,2112): m*8 + ks   (cols padded 8->16 with zeros)
// Wc   blocks [2112,2496): ct*24 + ks (ct 0..15, ks 0..23)
// ---------------------------------------------------------------------------
__global__ __launch_bounds__(256) void swizzle_kernel(
    const float* __restrict__ Wmax, const float* __restrict__ Wphi,
    const float* __restrict__ Wb,   const float* __restrict__ Wc,
    u16* __restrict__ ws)
{
  int sb   = blockIdx.x * 4 + (threadIdx.x >> 6);
  int lane = threadIdx.x & 63;
  int quad = lane >> 4, c16 = lane & 15;
  U16x8 o;
  if (sb < WB_B) {                       // Wmax or Wphi
    const float* W = (sb < WPHI_B) ? Wmax : Wphi;
    int b = sb & 1023;
    int m = b >> 7, r = b & 127;
    int ct = r >> 3, ks = r & 7;
    const float* src = W + ((size_t)m * DDIM + (size_t)(ks * 32 + quad * 8)) * DDIM
                         + ct * 16 + c16;
    #pragma unroll
    for (int j = 0; j < 8; ++j) o.u[j] = f2bf(src[j * DDIM]);
  } else if (sb < WC_B) {                // Wb, zero-padded to 16 cols
    int ksg = sb - WB_B;
    int kbase = ksg * 32 + quad * 8;
    if (c16 < 8) {
      #pragma unroll
      for (int j = 0; j < 8; ++j) o.u[j] = f2bf(Wb[(size_t)(kbase + j) * 8 + c16]);
    } else {
      o.q = make_uint4(0, 0, 0, 0);
    }
  } else {                               // Wc
    int r = sb - WC_B;
    int ct = r / 24, ks = r % 24;
    const float* src = Wc + (size_t)(ks * 32 + quad * 8) * DDIM + ct * 16 + c16;
    #pragma unroll
    for (int j = 0; j < 8; ++j) o.u[j] = f2bf(src[j * DDIM]);
  }
  *(uint4*)(ws + (size_t)sb * 512 + lane * 8) = o.q;
}

// ---------------------------------------------------------------------------
// Fused main kernel: 32 nodes per block, 256 threads = 4 waves.
// Wave w owns output cols [w*64, w*64+64).
// A-frag layout: lane l holds A[row=l&15][k=(l>>4)*8+j].
// C/D layout:    lane l, reg r -> row=(l>>4)*4+r, col=l&15.  [m89-verified]
// LDS tile chunk (frag f, quad q, row-low lr): slot = q*16 + (lr ^ (ks&15))
//   (XOR swizzle keeps staging ds_write_b128 at <=4-way bank conflict)
// ---------------------------------------------------------------------------
__global__ __launch_bounds__(256, 2) void fused_kernel(
    const float* __restrict__ zs,   const float* __restrict__ bb,
    const float* __restrict__ bmax, const float* __restrict__ bphi,
    const float* __restrict__ bc,   const float* __restrict__ gma,
    const float* __restrict__ bta,  const u16* __restrict__ ws,
    float* __restrict__ out, int N)
{
  const int tid  = threadIdx.x;
  const int lane = tid & 63;
  const int w    = tid >> 6;
  const int quad = lane >> 4;
  const int c16  = lane & 15;
  const int n0   = blockIdx.x * TROWS;
  const int zrow = tid >> 3;          // 0..31
  const int zseg = tid & 7;           // 0..7  (32-col segment)
  const int zlr  = zrow & 15, zrt = zrow >> 4;

  __shared__ __align__(16) u16 s_big[TROWS * 768];   // 48KB: tile / A' / zbuf
  __shared__ float s_lpart[4][TROWS][16];
  __shared__ float s_gate[TROWS][8];
  __shared__ float s_lnred[TROWS][8][2];
  __shared__ float s_mrs[TROWS][2];

  const f32x4 vzero = {0.f, 0.f, 0.f, 0.f};
  const f32x4 vninf = {-3e38f, -3e38f, -3e38f, -3e38f};

  // ================= Pass 1: gate logits (A-frags straight from global) ======
  f32x4 lf0 = vzero, lf1 = vzero;
  for (int m = 0; m < MREL; ++m) {
    #pragma unroll
    for (int kk = 0; kk < 2; ++kk) {
      const int ks = 2 * w + kk;   // waves split the 8 K-slabs of this relation
      U16x8 bu;
      bu.q = *(const uint4*)(ws + (size_t)(WB_B + m * 8 + ks) * 512 + lane * 8);
      #pragma unroll
      for (int rt = 0; rt < 2; ++rt) {
        int row = n0 + rt * 16 + c16;
        U16x8 au;
        if (row < N) {
          const float* p = zs + ((size_t)m * N + row) * DDIM + ks * 32 + quad * 8;
          float4 f0 = *(const float4*)p;
          float4 f1 = *(const float4*)(p + 4);
          au.u[0] = f2bf(f0.x); au.u[1] = f2bf(f0.y);
          au.u[2] = f2bf(f0.z); au.u[3] = f2bf(f0.w);
          au.u[4] = f2bf(f1.x); au.u[5] = f2bf(f1.y);
          au.u[6] = f2bf(f1.z); au.u[7] = f2bf(f1.w);
        } else {
          au.q = make_uint4(0, 0, 0, 0);
        }
        if (rt == 0) lf0 = __builtin_amdgcn_mfma_f32_16x16x32_bf16(au.v, bu.v, lf0, 0, 0, 0);
        else         lf1 = __builtin_amdgcn_mfma_f32_16x16x32_bf16(au.v, bu.v, lf1, 0, 0, 0);
      }
    }
  }
  #pragma unroll
  for (int r = 0; r < 4; ++r) {
    s_lpart[w][quad * 4 + r][c16]      = lf0[r];
    s_lpart[w][16 + quad * 4 + r][c16] = lf1[r];
  }
  __syncthreads();
  if (tid < TROWS) {                    // softmax over 8 relations, per row
    float lg[8]; float mx = -1e30f;
    #pragma unroll
    for (int mm = 0; mm < 8; ++mm) {
      float v = bb[mm] + s_lpart[0][tid][mm] + s_lpart[1][tid][mm]
                       + s_lpart[2][tid][mm] + s_lpart[3][tid][mm];
      lg[mm] = v; mx = fmaxf(mx, v);
    }
    float s = 0.f;
    #pragma unroll
    for (int mm = 0; mm < 8; ++mm) { lg[mm] = __expf(lg[mm] - mx); s += lg[mm]; }
    float inv = 1.f / s;
    #pragma unroll
    for (int mm = 0; mm < 8; ++mm) s_gate[tid][mm] = lg[mm] * inv;
  }

  // ================= Pass 2: proj/phi MFMAs + z_sum ==========================
  f32x4 zmx[2][4], s1v[2][4], s2v[2][4];
  #pragma unroll
  for (int rt = 0; rt < 2; ++rt)
    #pragma unroll
    for (int ct = 0; ct < 4; ++ct) {
      zmx[rt][ct] = vninf; s1v[rt][ct] = vzero; s2v[rt][ct] = vzero;
    }
  float zsum[32];
  #pragma unroll
  for (int i = 0; i < 32; ++i) zsum[i] = 0.f;

  const int st_r8 = tid >> 5;           // staging: 0..7
  const int st_d  = (tid & 31) * 8;     // staging col base
  const int st_ks = st_d >> 5;
  const int st_q  = (st_d >> 3) & 3;

  for (int m = 0; m < MREL; ++m) {
    __syncthreads();                    // tile reuse fence (also orders s_gate)
    #pragma unroll
    for (int it = 0; it < 4; ++it) {    // stage 32x256 fp32 -> bf16 frag-order
      int rl = it * 8 + st_r8;
      int row = n0 + rl;
      U16x8 pk;
      if (row < N) {
        const float* p = zs + ((size_t)m * N + row) * DDIM + st_d;
        float4 f0 = *(const float4*)p;
        float4 f1 = *(const float4*)(p + 4);
        pk.u[0] = f2bf(f0.x); pk.u[1] = f2bf(f0.y);
        pk.u[2] = f2bf(f0.z); pk.u[3] = f2bf(f0.w);
        pk.u[4] = f2bf(f1.x); pk.u[5] = f2bf(f1.y);
        pk.u[6] = f2bf(f1.z); pk.u[7] = f2bf(f1.w);
      } else pk.q = make_uint4(0, 0, 0, 0);
      int lr = rl & 15, rt = rl >> 4;
      *(uint4*)(s_big + (rt * 8 + st_ks) * 512 + (st_q * 16 + (lr ^ st_ks)) * 8) = pk.q;
    }
    __syncthreads();

    #pragma unroll
    for (int sel = 0; sel < 2; ++sel) { // 0: Wmax->z_max, 1: Wphi->s1/s2
      f32x4 pa[2][4];
      #pragma unroll
      for (int rt = 0; rt < 2; ++rt)
        #pragma unroll
        for (int ct = 0; ct < 4; ++ct) pa[rt][ct] = vzero;
      const int bbase = (sel ? WPHI_B : 0) + m * 128 + w * 32;
      #pragma unroll
      for (int ks = 0; ks < 8; ++ks) {
        U16x8 a0, a1;
        a0.q = *(const uint4*)(s_big + ks * 512       + (quad * 16 + (c16 ^ ks)) * 8);
        a1.q = *(const uint4*)(s_big + (8 + ks) * 512 + (quad * 16 + (c16 ^ ks)) * 8);
        #pragma unroll
        for (int ct = 0; ct < 4; ++ct) {
          U16x8 bu;
          bu.q = *(const uint4*)(ws + (size_t)(bbase + ct * 8 + ks) * 512 + lane * 8);
          pa[0][ct] = __builtin_amdgcn_mfma_f32_16x16x32_bf16(a0.v, bu.v, pa[0][ct], 0, 0, 0);
          pa[1][ct] = __builtin_amdgcn_mfma_f32_16x16x32_bf16(a1.v, bu.v, pa[1][ct], 0, 0, 0);
        }
      }
      #pragma unroll
      for (int ct = 0; ct < 4; ++ct) {
        int col = (w * 4 + ct) * 16 + c16;
        float bias = sel ? bphi[m * DDIM + col] : bmax[m * DDIM + col];
        #pragma unroll
        for (int rt = 0; rt < 2; ++rt)
          #pragma unroll
          for (int r = 0; r < 4; ++r) {
            float v = pa[rt][ct][r] + bias;
            if (sel == 0) { zmx[rt][ct][r] = fmaxf(zmx[rt][ct][r], v); }
            else          { s1v[rt][ct][r] += v; s2v[rt][ct][r] += v * v; }
          }
      }
    }

    { // z_sum += gate[n][m] * zs[m][n][:]
      float g = s_gate[zrow][m];
      #pragma unroll
      for (int c = 0; c < 4; ++c) {
        U16x8 v;
        v.q = *(const uint4*)(s_big + (zrt * 8 + zseg) * 512 + (c * 16 + (zlr ^ zseg)) * 8);
        #pragma unroll
        for (int j = 0; j < 8; ++j) zsum[c * 8 + j] += g * bf2f(v.u[j]);
      }
    }
  }
  __syncthreads();

  // ========== Build A' = [z_sum | z_max | z_agr] (32x768 bf16, frag order) ===
  #pragma unroll
  for (int c = 0; c < 4; ++c) {
    U16x8 pk;
    #pragma unroll
    for (int j = 0; j < 8; ++j) pk.u[j] = f2bf(zsum[c * 8 + j]);
    *(uint4*)(s_big + (zrt * 24 + zseg) * 512 + (c * 16 + (zlr ^ zseg)) * 8) = pk.q;
  }
  #pragma unroll
  for (int ct = 0; ct < 4; ++ct) {
    int col = (w * 4 + ct) * 16 + c16;
    int k1 = 256 + col, k2 = 512 + col;
    int ks1 = k1 >> 5, q1 = (k1 >> 3) & 3, j1 = k1 & 7;
    int ks2 = k2 >> 5, q2 = (k2 >> 3) & 3, j2 = k2 & 7;
    #pragma unroll
    for (int rt = 0; rt < 2; ++rt)
      #pragma unroll
      for (int r = 0; r < 4; ++r) {
        int lr = quad * 4 + r;
        s_big[(rt * 24 + ks1) * 512 + (q1 * 16 + (lr ^ (ks1 & 15))) * 8 + j1] =
            f2bf(zmx[rt][ct][r]);
        float za = 0.5f * (s1v[rt][ct][r] * s1v[rt][ct][r] - s2v[rt][ct][r]);
        s_big[(rt * 24 + ks2) * 512 + (q2 * 16 + (lr ^ (ks2 & 15))) * 8 + j2] =
            f2bf(za);
      }
  }
  __syncthreads();

  // ================= Combine GEMM: A'(32x768) @ Wc(768x256) ==================
  f32x4 oc[2][4];
  #pragma unroll
  for (int rt = 0; rt < 2; ++rt)
    #pragma unroll
    for (int ct = 0; ct < 4; ++ct) oc[rt][ct] = vzero;
  for (int ks = 0; ks < 24; ++ks) {
    int x = ks & 15;
    U16x8 a0, a1;
    a0.q = *(const uint4*)(s_big + ks * 512        + (quad * 16 + (c16 ^ x)) * 8);
    a1.q = *(const uint4*)(s_big + (24 + ks) * 512 + (quad * 16 + (c16 ^ x)) * 8);
    #pragma unroll
    for (int ct = 0; ct < 4; ++ct) {
      U16x8 bu;
      bu.q = *(const uint4*)(ws + (size_t)(WC_B + (w * 4 + ct) * 24 + ks) * 512 + lane * 8);
      oc[0][ct] = __builtin_amdgcn_mfma_f32_16x16x32_bf16(a0.v, bu.v, oc[0][ct], 0, 0, 0);
      oc[1][ct] = __builtin_amdgcn_mfma_f32_16x16x32_bf16(a1.v, bu.v, oc[1][ct], 0, 0, 0);
    }
  }
  __syncthreads();                       // done reading A'

  // ================= + bc, LayerNorm, store ==================================
  float* zbuf = (float*)s_big;           // 32 x 264 (pad 8 breaks bank stride)
  #pragma unroll
  for (int ct = 0; ct < 4; ++ct) {
    int col = (w * 4 + ct) * 16 + c16;
    float bcv = bc[col];
    #pragma unroll
    for (int rt = 0; rt < 2; ++rt)
      #pragma unroll
      for (int r = 0; r < 4; ++r)
        zbuf[(rt * 16 + quad * 4 + r) * 264 + col] = oc[rt][ct][r] + bcv;
  }
  __syncthreads();
  {
    float s = 0.f, ss = 0.f;
    const float* zp = zbuf + zrow * 264 + zseg * 32;
    #pragma unroll
    for (int c = 0; c < 8; ++c) {
      float4 v = *(const float4*)(zp + c * 4);
      s  += v.x + v.y + v.z + v.w;
      ss += v.x * v.x + v.y * v.y + v.z * v.z + v.w * v.w;
    }
    s_lnred[zrow][zseg][0] = s; s_lnred[zrow][zseg][1] = ss;
  }
  __syncthreads();
  if (tid < TROWS) {
    float s = 0.f, ss = 0.f;
    #pragma unroll
    for (int g = 0; g < 8; ++g) { s += s_lnred[tid][g][0]; ss += s_lnred[tid][g][1]; }
    float mu  = s * (1.0f / 256.0f);
    float var = ss * (1.0f / 256.0f) - mu * mu;
    s_mrs[tid][0] = mu;
    s_mrs[tid][1] = rsqrtf(var + 1e-5f);
  }
  __syncthreads();
  {
    int row = n0 + zrow;
    if (row < N) {
      float mu = s_mrs[zrow][0], rs = s_mrs[zrow][1];
      const float* zp = zbuf + zrow * 264 + zseg * 32;
      float* op = out + (size_t)row * DDIM + zseg * 32;
      #pragma unroll
      for (int c = 0; c < 8; ++c) {
        float4 v  = *(const float4*)(zp + c * 4);
        float4 gm = *(const float4*)(gma + zseg * 32 + c * 4);
        float4 bt = *(const float4*)(bta + zseg * 32 + c * 4);
        float4 o;
        o.x = (v.x - mu) * rs * gm.x + bt.x;
        o.y = (v.y - mu) * rs * gm.y + bt.y;
        o.z = (v.z - mu) * rs * gm.z + bt.z;
        o.w = (v.w - mu) * rs * gm.w + bt.w;
        *(float4*)(op + c * 4) = o;
      }
    }
  }
}

extern "C" void kernel_launch(void* const* d_in, const int* in_sizes, int n_in,
                              void* d_out, int out_size, void* d_ws, size_t ws_size,
                              hipStream_t stream) {
  const float* zs   = (const float*)d_in[0];
  const float* Wb   = (const float*)d_in[1];
  const float* bb   = (const float*)d_in[2];
  const float* Wmax = (const float*)d_in[3];
  const float* bmax = (const float*)d_in[4];
  const float* Wphi = (const float*)d_in[5];
  const float* bphi = (const float*)d_in[6];
  const float* Wc   = (const float*)d_in[7];
  const float* bc   = (const float*)d_in[8];
  const float* gma  = (const float*)d_in[9];
  const float* bta  = (const float*)d_in[10];
  float* out = (float*)d_out;
  u16* ws = (u16*)d_ws;

  int N = in_sizes[0] / (MREL * DDIM);

  swizzle_kernel<<<NBLK / 4, 256, 0, stream>>>(Wmax, Wphi, Wb, Wc, ws);
  int grid = (N + TROWS - 1) / TROWS;
  fused_kernel<<<grid, 256, 0, stream>>>(zs, bb, bmax, bphi, bc, gma, bta, ws, out, N);
}

// Round 2
// 1154.458 us; speedup vs baseline: 1.0282x; 1.0282x over previous
//
#include <hip/hip_runtime.h>

typedef unsigned short u16;
typedef unsigned int   u32;
typedef __attribute__((ext_vector_type(8))) __bf16 bf16x8;
typedef __attribute__((ext_vector_type(4))) float  f32x4;

#define MREL  8
#define DDIM  256
#define TROWS 32

// ws block layout: each block = 512 u16 = 1KB (one B-fragment set: 64 lanes x 8 bf16)
#define WPHI_B 1024
#define WB_B   2048
#define WC_B   2112
#define NBLK   2496

__device__ __forceinline__ u16 f2bf(float x) {
  u32 u = __float_as_uint(x);
  u += 0x7fffu + ((u >> 16) & 1u);   // RNE
  return (u16)(u >> 16);
}

union U16x8 { u16 u[8]; uint4 q; bf16x8 v; };

// chunk slot inside a 512-u16 ks-group; q=col-quad(0..3), lr=row(0..15), ks=k-slab
// XOR with q<<1 spreads bank residues across the 4 q values (staging writes were
// 4-way conflicted with plain lr^ks).
#define SLOT(q, lr, ks) ((q)*16 + ((((lr) ^ (ks)) ^ ((q) << 1)) & 15))

// ---------------------------------------------------------------------------
// Prologue: swizzle all weights into bf16 MFMA B-fragment order.
// B-frag layout (16x16x32): lane l holds B[k=(l>>4)*8+j][col=l&15], j=0..7.
// ---------------------------------------------------------------------------
__global__ __launch_bounds__(256) void swizzle_kernel(
    const float* __restrict__ Wmax, const float* __restrict__ Wphi,
    const float* __restrict__ Wb,   const float* __restrict__ Wc,
    u16* __restrict__ ws)
{
  int sb   = blockIdx.x * 4 + (threadIdx.x >> 6);
  int lane = threadIdx.x & 63;
  int quad = lane >> 4, c16 = lane & 15;
  U16x8 o;
  if (sb < WB_B) {                       // Wmax or Wphi
    const float* W = (sb < WPHI_B) ? Wmax : Wphi;
    int b = sb & 1023;
    int m = b >> 7, r = b & 127;
    int ct = r >> 3, ks = r & 7;
    const float* src = W + ((size_t)m * DDIM + (size_t)(ks * 32 + quad * 8)) * DDIM
                         + ct * 16 + c16;
    #pragma unroll
    for (int j = 0; j < 8; ++j) o.u[j] = f2bf(src[j * DDIM]);
  } else if (sb < WC_B) {                // Wb, zero-padded to 16 cols
    int ksg = sb - WB_B;
    int kbase = ksg * 32 + quad * 8;
    if (c16 < 8) {
      #pragma unroll
      for (int j = 0; j < 8; ++j) o.u[j] = f2bf(Wb[(size_t)(kbase + j) * 8 + c16]);
    } else {
      o.q = make_uint4(0, 0, 0, 0);
    }
  } else {                               // Wc
    int r = sb - WC_B;
    int ct = r / 24, ks = r % 24;
    const float* src = Wc + (size_t)(ks * 32 + quad * 8) * DDIM + ct * 16 + c16;
    #pragma unroll
    for (int j = 0; j < 8; ++j) o.u[j] = f2bf(src[j * DDIM]);
  }
  *(uint4*)(ws + (size_t)sb * 512 + lane * 8) = o.q;
}

// ---------------------------------------------------------------------------
// Fused main kernel: 32 nodes/block, 4 waves; wave w owns output cols [w*64,w*64+64).
// A-frag: lane l holds A[row=l&15][k=(l>>4)*8+j].  C/D: row=(l>>4)*4+r, col=l&15.
// Loop A: staged tile -> gate-logit + Wmax/Wphi MFMAs, prefetched staging (dbuf).
// Loop B: streaming z_sum (coalesced, no LDS).  Combine: 3 K=256 pieces through
// one 16KB buffer.  LN: shfl reduction, no zbuf.
// ---------------------------------------------------------------------------
__global__ __launch_bounds__(256, 2) void fused_kernel(
    const float* __restrict__ zs,   const float* __restrict__ bb,
    const float* __restrict__ bmax, const float* __restrict__ bphi,
    const float* __restrict__ bc,   const float* __restrict__ gma,
    const float* __restrict__ bta,  const u16* __restrict__ ws,
    float* __restrict__ out, int N)
{
  const int tid  = threadIdx.x;
  const int lane = tid & 63;
  const int w    = tid >> 6;
  const int quad = lane >> 4;
  const int c16  = lane & 15;
  const int n0   = blockIdx.x * TROWS;
  const int zrow = tid >> 3;          // 0..31
  const int zseg = tid & 7;           // 0..7
  const int st_r8 = tid >> 5;         // staging row slot 0..7
  const int sl    = tid & 31;         // staging col lane
  const int st_ks = sl >> 2;
  const int st_q  = sl & 3;

  __shared__ __align__(16) u16 s_tile[16384];   // 32KB = two 16KB tile buffers
  __shared__ float s_gate[TROWS][8];
  __shared__ float s_ln1[TROWS][4];
  __shared__ float s_ln2[TROWS][4];
  __shared__ float s_mrs[TROWS][2];
  float* s_lpartF = (float*)s_tile;             // [4][32][16] aliases buf0 (dead then)

  const f32x4 vz = {0.f, 0.f, 0.f, 0.f};
  f32x4 zmx[2][4], s1v[2][4], s2v[2][4];
  #pragma unroll
  for (int rt = 0; rt < 2; ++rt)
    #pragma unroll
    for (int ct = 0; ct < 4; ++ct) {
      zmx[rt][ct] = (f32x4){-3e38f, -3e38f, -3e38f, -3e38f};
      s1v[rt][ct] = vz; s2v[rt][ct] = vz;
    }
  f32x4 lf0 = vz, lf1 = vz;

  float4 F[8];
  auto issue_loads = [&](int m) {
    const float* base = zs + (size_t)m * N * DDIM;
    #pragma unroll
    for (int it = 0; it < 4; ++it) {
      int rl = it * 8 + st_r8;
      int row = n0 + rl;
      if (row < N) {
        const float* p = base + (size_t)row * DDIM + sl * 8;
        F[it * 2]     = *(const float4*)p;
        F[it * 2 + 1] = *(const float4*)(p + 4);
      } else {
        F[it * 2] = make_float4(0.f, 0.f, 0.f, 0.f);
        F[it * 2 + 1] = make_float4(0.f, 0.f, 0.f, 0.f);
      }
    }
  };
  auto write_tile = [&](u16* buf) {
    #pragma unroll
    for (int it = 0; it < 4; ++it) {
      int rl = it * 8 + st_r8;
      int lr = rl & 15, rt = rl >> 4;
      float4 f0 = F[it * 2], f1 = F[it * 2 + 1];
      U16x8 pk;
      pk.u[0] = f2bf(f0.x); pk.u[1] = f2bf(f0.y);
      pk.u[2] = f2bf(f0.z); pk.u[3] = f2bf(f0.w);
      pk.u[4] = f2bf(f1.x); pk.u[5] = f2bf(f1.y);
      pk.u[6] = f2bf(f1.z); pk.u[7] = f2bf(f1.w);
      *(uint4*)(buf + (rt * 8 + st_ks) * 512 + SLOT(st_q, lr, st_ks) * 8) = pk.q;
    }
  };

  // ================= Loop A =================================================
  issue_loads(0);
  for (int m = 0; m < MREL; ++m) {
    u16* buf = s_tile + (m & 1) * 8192;
    write_tile(buf);
    __syncthreads();
    if (m < MREL - 1) issue_loads(m + 1);   // in flight during compute below

    f32x4 pa[2][4];
    // ---- sel 0: Wmax (+ gate logits on this wave's ks slice) ----
    #pragma unroll
    for (int rt = 0; rt < 2; ++rt)
      #pragma unroll
      for (int ct = 0; ct < 4; ++ct) pa[rt][ct] = vz;
    {
      const int bbase = m * 128 + w * 32;
      #pragma unroll
      for (int ks = 0; ks < 8; ++ks) {
        U16x8 a0, a1;
        int so = SLOT(quad, c16, ks) * 8;
        a0.q = *(const uint4*)(buf + ks * 512 + so);
        a1.q = *(const uint4*)(buf + (8 + ks) * 512 + so);
        if ((ks >> 1) == w) {
          U16x8 bg;
          bg.q = *(const uint4*)(ws + (size_t)(WB_B + m * 8 + ks) * 512 + lane * 8);
          lf0 = __builtin_amdgcn_mfma_f32_16x16x32_bf16(a0.v, bg.v, lf0, 0, 0, 0);
          lf1 = __builtin_amdgcn_mfma_f32_16x16x32_bf16(a1.v, bg.v, lf1, 0, 0, 0);
        }
        #pragma unroll
        for (int ct = 0; ct < 4; ++ct) {
          U16x8 bu;
          bu.q = *(const uint4*)(ws + (size_t)(bbase + ct * 8 + ks) * 512 + lane * 8);
          pa[0][ct] = __builtin_amdgcn_mfma_f32_16x16x32_bf16(a0.v, bu.v, pa[0][ct], 0, 0, 0);
          pa[1][ct] = __builtin_amdgcn_mfma_f32_16x16x32_bf16(a1.v, bu.v, pa[1][ct], 0, 0, 0);
        }
      }
      #pragma unroll
      for (int ct = 0; ct < 4; ++ct) {
        float b = bmax[m * DDIM + (w * 4 + ct) * 16 + c16];
        #pragma unroll
        for (int rt = 0; rt < 2; ++rt)
          #pragma unroll
          for (int r = 0; r < 4; ++r)
            zmx[rt][ct][r] = fmaxf(zmx[rt][ct][r], pa[rt][ct][r] + b);
      }
    }
    // ---- sel 1: Wphi ----
    #pragma unroll
    for (int rt = 0; rt < 2; ++rt)
      #pragma unroll
      for (int ct = 0; ct < 4; ++ct) pa[rt][ct] = vz;
    {
      const int bbase = WPHI_B + m * 128 + w * 32;
      #pragma unroll
      for (int ks = 0; ks < 8; ++ks) {
        U16x8 a0, a1;
        int so = SLOT(quad, c16, ks) * 8;
        a0.q = *(const uint4*)(buf + ks * 512 + so);
        a1.q = *(const uint4*)(buf + (8 + ks) * 512 + so);
        #pragma unroll
        for (int ct = 0; ct < 4; ++ct) {
          U16x8 bu;
          bu.q = *(const uint4*)(ws + (size_t)(bbase + ct * 8 + ks) * 512 + lane * 8);
          pa[0][ct] = __builtin_amdgcn_mfma_f32_16x16x32_bf16(a0.v, bu.v, pa[0][ct], 0, 0, 0);
          pa[1][ct] = __builtin_amdgcn_mfma_f32_16x16x32_bf16(a1.v, bu.v, pa[1][ct], 0, 0, 0);
        }
      }
      #pragma unroll
      for (int ct = 0; ct < 4; ++ct) {
        float b = bphi[m * DDIM + (w * 4 + ct) * 16 + c16];
        #pragma unroll
        for (int rt = 0; rt < 2; ++rt)
          #pragma unroll
          for (int r = 0; r < 4; ++r) {
            float v = pa[rt][ct][r] + b;
            s1v[rt][ct][r] += v;
            s2v[rt][ct][r] += v * v;
          }
      }
    }
  }

  // ================= softmax gate ===========================================
  #pragma unroll
  for (int r = 0; r < 4; ++r) {
    s_lpartF[(w * 32 + quad * 4 + r) * 16 + c16]      = lf0[r];
    s_lpartF[(w * 32 + 16 + quad * 4 + r) * 16 + c16] = lf1[r];
  }
  __syncthreads();
  if (tid < TROWS) {
    float lg[8]; float mx = -1e30f;
    #pragma unroll
    for (int mm = 0; mm < 8; ++mm) {
      float v = bb[mm] + s_lpartF[(0 * 32 + tid) * 16 + mm]
                       + s_lpartF[(1 * 32 + tid) * 16 + mm]
                       + s_lpartF[(2 * 32 + tid) * 16 + mm]
                       + s_lpartF[(3 * 32 + tid) * 16 + mm];
      lg[mm] = v; mx = fmaxf(mx, v);
    }
    float s = 0.f;
    #pragma unroll
    for (int mm = 0; mm < 8; ++mm) { lg[mm] = __expf(lg[mm] - mx); s += lg[mm]; }
    float inv = 1.f / s;
    #pragma unroll
    for (int mm = 0; mm < 8; ++mm) s_gate[tid][mm] = lg[mm] * inv;
  }
  __syncthreads();

  // ================= Loop B: streaming z_sum ================================
  float zsum[32];
  #pragma unroll
  for (int i = 0; i < 32; ++i) zsum[i] = 0.f;
  {
    int row = n0 + zrow;
    if (row < N) {
      #pragma unroll
      for (int m = 0; m < MREL; ++m) {
        float g = s_gate[zrow][m];
        const float* p = zs + ((size_t)m * N + row) * DDIM + zseg * 32;
        #pragma unroll
        for (int c = 0; c < 8; ++c) {
          float4 v = *(const float4*)(p + c * 4);
          zsum[c * 4 + 0] += g * v.x; zsum[c * 4 + 1] += g * v.y;
          zsum[c * 4 + 2] += g * v.z; zsum[c * 4 + 3] += g * v.w;
        }
      }
    }
  }

  // ================= Combine GEMM in 3 K=256 pieces =========================
  u16* buf0 = s_tile;
  f32x4 oc[2][4];
  #pragma unroll
  for (int rt = 0; rt < 2; ++rt)
    #pragma unroll
    for (int ct = 0; ct < 4; ++ct) oc[rt][ct] = vz;

  auto combine_piece = [&](int p) {
    #pragma unroll
    for (int ks = 0; ks < 8; ++ks) {
      U16x8 a0, a1;
      int so = SLOT(quad, c16, ks) * 8;
      a0.q = *(const uint4*)(buf0 + ks * 512 + so);
      a1.q = *(const uint4*)(buf0 + (8 + ks) * 512 + so);
      #pragma unroll
      for (int ct = 0; ct < 4; ++ct) {
        U16x8 bu;
        bu.q = *(const uint4*)(ws + (size_t)(WC_B + (w * 4 + ct) * 24 + p * 8 + ks) * 512
                               + lane * 8);
        oc[0][ct] = __builtin_amdgcn_mfma_f32_16x16x32_bf16(a0.v, bu.v, oc[0][ct], 0, 0, 0);
        oc[1][ct] = __builtin_amdgcn_mfma_f32_16x16x32_bf16(a1.v, bu.v, oc[1][ct], 0, 0, 0);
      }
    }
  };

  // piece 0: z_sum (thread owns row zrow, cols zseg*32..+31)
  {
    int lr = zrow & 15, rt = zrow >> 4;
    #pragma unroll
    for (int cc = 0; cc < 4; ++cc) {
      U16x8 pk;
      #pragma unroll
      for (int k = 0; k < 8; ++k) pk.u[k] = f2bf(zsum[cc * 8 + k]);
      *(uint4*)(buf0 + (rt * 8 + zseg) * 512 + SLOT(cc, lr, zseg) * 8) = pk.q;
    }
  }
  __syncthreads();
  combine_piece(0);
  __syncthreads();

  // piece 1: z_max (C-frag layout -> scalar u16 writes)
  #pragma unroll
  for (int ct = 0; ct < 4; ++ct) {
    int col = (w * 4 + ct) * 16 + c16;
    int ks = col >> 5, q = (col >> 3) & 3, j = col & 7;
    #pragma unroll
    for (int rt = 0; rt < 2; ++rt)
      #pragma unroll
      for (int r = 0; r < 4; ++r) {
        int lr = quad * 4 + r;
        buf0[(rt * 8 + ks) * 512 + SLOT(q, lr, ks) * 8 + j] = f2bf(zmx[rt][ct][r]);
      }
  }
  __syncthreads();
  combine_piece(1);
  __syncthreads();

  // piece 2: z_agr = 0.5*(s1^2 - s2)
  #pragma unroll
  for (int ct = 0; ct < 4; ++ct) {
    int col = (w * 4 + ct) * 16 + c16;
    int ks = col >> 5, q = (col >> 3) & 3, j = col & 7;
    #pragma unroll
    for (int rt = 0; rt < 2; ++rt)
      #pragma unroll
      for (int r = 0; r < 4; ++r) {
        int lr = quad * 4 + r;
        float za = 0.5f * (s1v[rt][ct][r] * s1v[rt][ct][r] - s2v[rt][ct][r]);
        buf0[(rt * 8 + ks) * 512 + SLOT(q, lr, ks) * 8 + j] = f2bf(za);
      }
  }
  __syncthreads();
  combine_piece(2);

  // ================= + bc, LayerNorm (register/shfl), store =================
  #pragma unroll
  for (int ct = 0; ct < 4; ++ct) {
    float bcv = bc[(w * 4 + ct) * 16 + c16];
    #pragma unroll
    for (int rt = 0; rt < 2; ++rt)
      #pragma unroll
      for (int r = 0; r < 4; ++r) oc[rt][ct][r] += bcv;
  }
  float ps[2][4], pss[2][4];
  #pragma unroll
  for (int rt = 0; rt < 2; ++rt)
    #pragma unroll
    for (int r = 0; r < 4; ++r) {
      float s = 0.f, ss = 0.f;
      #pragma unroll
      for (int ct = 0; ct < 4; ++ct) {
        float v = oc[rt][ct][r];
        s += v; ss += v * v;
      }
      ps[rt][r] = s; pss[rt][r] = ss;
    }
  #pragma unroll
  for (int off = 1; off < 16; off <<= 1) {
    #pragma unroll
    for (int rt = 0; rt < 2; ++rt)
      #pragma unroll
      for (int r = 0; r < 4; ++r) {
        ps[rt][r]  += __shfl_xor(ps[rt][r], off);
        pss[rt][r] += __shfl_xor(pss[rt][r], off);
      }
  }
  if (c16 == 0) {
    #pragma unroll
    for (int rt = 0; rt < 2; ++rt)
      #pragma unroll
      for (int r = 0; r < 4; ++r) s_ln1[rt * 16 + quad * 4 + r][w] = ps[rt][r];
  }
  if (c16 == 1) {
    #pragma unroll
    for (int rt = 0; rt < 2; ++rt)
      #pragma unroll
      for (int r = 0; r < 4; ++r) s_ln2[rt * 16 + quad * 4 + r][w] = pss[rt][r];
  }
  __syncthreads();
  if (tid < TROWS) {
    float s  = s_ln1[tid][0] + s_ln1[tid][1] + s_ln1[tid][2] + s_ln1[tid][3];
    float ss = s_ln2[tid][0] + s_ln2[tid][1] + s_ln2[tid][2] + s_ln2[tid][3];
    float mu  = s * (1.0f / 256.0f);
    float var = ss * (1.0f / 256.0f) - mu * mu;
    s_mrs[tid][0] = mu;
    s_mrs[tid][1] = rsqrtf(var + 1e-5f);
  }
  __syncthreads();
  #pragma unroll
  for (int ct = 0; ct < 4; ++ct) {
    int col = (w * 4 + ct) * 16 + c16;
    float g = gma[col], b = bta[col];
    #pragma unroll
    for (int rt = 0; rt < 2; ++rt)
      #pragma unroll
      for (int r = 0; r < 4; ++r) {
        int row = rt * 16 + quad * 4 + r;
        int grow = n0 + row;
        if (grow < N) {
          float mu = s_mrs[row][0], rs = s_mrs[row][1];
          out[(size_t)grow * DDIM + col] = (oc[rt][ct][r] - mu) * rs * g + b;
        }
      }
  }
}

extern "C" void kernel_launch(void* const* d_in, const int* in_sizes, int n_in,
                              void* d_out, int out_size, void* d_ws, size_t ws_size,
                              hipStream_t stream) {
  const float* zs   = (const float*)d_in[0];
  const float* Wb   = (const float*)d_in[1];
  const float* bb   = (const float*)d_in[2];
  const float* Wmax = (const float*)d_in[3];
  const float* bmax = (const float*)d_in[4];
  const float* Wphi = (const float*)d_in[5];
  const float* bphi = (const float*)d_in[6];
  const float* Wc   = (const float*)d_in[7];
  const float* bc   = (const float*)d_in[8];
  const float* gma  = (const float*)d_in[9];
  const float* bta  = (const float*)d_in[10];
  float* out = (float*)d_out;
  u16* ws = (u16*)d_ws;

  int N = in_sizes[0] / (MREL * DDIM);

  swizzle_kernel<<<NBLK / 4, 256, 0, stream>>>(Wmax, Wphi, Wb, Wc, ws);
  int grid = (N + TROWS - 1) / TROWS;
  fused_kernel<<<grid, 256, 0, stream>>>(zs, bb, bmax, bphi, bc, gma, bta, ws, out, N);
}